// Round 6
// baseline (184.035 us; speedup 1.0000x reference)
//
#include <hip/hip_runtime.h>
#include <hip/hip_bf16.h>
#include <math.h>

// Problem constants
#define Bn  4
#define Cc  64
#define MHc 18
#define Hh  128
#define Wd  128
#define HW  (Hh*Wd)
#define Np  9
#define HP  130
#define WP  130
#define XPE (HP*WP*Cc)     // xpad elems per batch (bf16): 1,081,600
#define PPE (HP*WP*32)     // popad/ropad elems per batch: 540,800
#define KX  576            // x-tap K (9*64)
#define KP  288            // po-tap K (9*32)
#define KT  (KX+KP)        // 864 total K, 27 MFMA steps

typedef __attribute__((ext_vector_type(8))) short short8;
typedef __attribute__((ext_vector_type(4))) float float4v;

__device__ __forceinline__ float bf2f(__hip_bfloat16 x) { return __bfloat162float(x); }
__device__ __forceinline__ __hip_bfloat16 f2bf(float x) { return __float2bfloat16(x); }
__device__ __forceinline__ float sigm(float x) { return 1.f / (1.f + expf(-x)); }
__device__ __forceinline__ float s2f(short s) {            // bf16 bits -> f32
  return __uint_as_float(((unsigned)(unsigned short)s) << 16);
}
__device__ __forceinline__ short f2bs(float x) {           // f32 -> bf16 bits (RNE)
  __hip_bfloat16 h = __float2bfloat16(x);
  return *reinterpret_cast<short*>(&h);
}

#define NW1 (64*KT)          // 55296
#define NW2 (32*KP)          // 9216
#define NW3 (Cc*Cc*Np)       // 36864  (total 101376 = 396*256)

// ---------------------------------------------------------------------------
// K1: prep. blk<512: x row-block | 512..1023: popad row | 1024..1419: weights
// | 1420..1431: border zeroing (only pad borders are load-bearing).
// ---------------------------------------------------------------------------
__global__ __launch_bounds__(256)
void k_prep(const float* __restrict__ x, const float* __restrict__ po,
            const float* __restrict__ upd_w, const float* __restrict__ rst_w,
            const float* __restrict__ out_w, const float* __restrict__ wg_w,
            const float* __restrict__ wcw,
            __hip_bfloat16* __restrict__ xp, __hip_bfloat16* __restrict__ pp,
            __hip_bfloat16* __restrict__ rp,
            __hip_bfloat16* __restrict__ wall, __hip_bfloat16* __restrict__ w2,
            __hip_bfloat16* __restrict__ wt) {
  __shared__ float tile[128][65];
  int blk = blockIdx.x;
  int t = threadIdx.x;
  if (blk < 512) {
    int b = blk >> 7, h = blk & 127;
    int c = t >> 2;
    int wbase = (t & 3) * 32;
    const float* src = &x[(b*Cc + c)*HW + h*Wd + wbase];
    #pragma unroll
    for (int j = 0; j < 8; ++j) {
      float4v v = *reinterpret_cast<const float4v*>(src + j*4);
      tile[wbase + j*4 + 0][c] = v.x;
      tile[wbase + j*4 + 1][c] = v.y;
      tile[wbase + j*4 + 2][c] = v.z;
      tile[wbase + j*4 + 3][c] = v.w;
    }
    __syncthreads();
    #pragma unroll
    for (int j = 0; j < 4; ++j) {
      int i = t + j * 256;
      int px = i >> 3, oct = i & 7;
      short8 ov;
      #pragma unroll
      for (int e = 0; e < 8; ++e) ov[e] = f2bs(tile[px][oct*8 + e]);
      *reinterpret_cast<short8*>(
          &xp[b*XPE + ((h+1)*WP + px + 1)*Cc + oct*8]) = ov;
    }
  } else if (blk < 1024) {
    int pb = blk - 512;             // b*128 + h
    int h = pb & 127;
    int b = pb >> 7;
    int w = t & 127;
    int half = t >> 7;
    float v[9];
    #pragma unroll
    for (int j = 0; j < 9; ++j)
      v[j] = po[(b*MHc + half*9 + j)*HW + h*Wd + w];
    #pragma unroll
    for (int j = 0; j < 9; ++j)
      pp[b*PPE + ((h+1)*WP + (w+1))*32 + half*9 + j] = f2bf(v[j]);
  } else if (blk < 1420) {
    int idx = (blk - 1024) * 256 + t;
    if (idx < NW1) {
      int k  = idx % KT;
      int gr = idx / KT;
      float v = 0.f;
      if (k < KX) {
        int n = k >> 6, ci = k & 63;
        if      (gr < 18) v = upd_w[(gr*(Cc+MHc) + ci)*9 + n];
        else if (gr < 36) v = rst_w[((gr-18)*(Cc+MHc) + ci)*9 + n];
        else if (gr < 54) v = out_w[((gr-36)*(Cc+MHc) + ci)*9 + n];
        else if (gr < 63) v = wg_w[((gr-54)*Cc + ci)*9 + n];
      } else {
        int kk = k - KX;
        int n = kk >> 5, jc = kk & 31;
        if (jc < 18) {
          if      (gr < 18) v = upd_w[(gr*(Cc+MHc) + Cc + jc)*9 + n];
          else if (gr < 36) v = rst_w[((gr-18)*(Cc+MHc) + Cc + jc)*9 + n];
        }
      }
      wall[idx] = f2bf(v);
    } else if (idx < NW1 + NW2) {
      int i2 = idx - NW1;
      int k  = i2 % KP;
      int oc = i2 / KP;
      int n = k >> 5, jc = k & 31;
      float v = (oc < 18 && jc < 18) ? out_w[(oc*(Cc+MHc) + Cc + jc)*9 + n] : 0.f;
      w2[i2] = f2bf(v);
    } else if (idx < NW1 + NW2 + NW3) {
      int i3 = idx - NW1 - NW2;
      int k  = i3 % 576;
      int co = i3 / 576;
      wt[i3] = f2bf(wcw[(co*Cc + (k & 63))*9 + (k >> 6)]);
    }
  } else {
    // border zero: bid 0..11 -> kind(4 blocks each): xpad / popad / ropad
    int bid = blk - 1420;
    int kind = bid >> 2;
    int b = bid & 3;
    short8 z = {0,0,0,0,0,0,0,0};
    if (kind == 0) {
      __hip_bfloat16* base = xp + b*XPE;
      for (int i = t; i < 4128; i += 256) {
        int off;
        if (i < 2080) {
          int row = (i < 1040) ? 0 : 129;
          int j = (i < 1040) ? i : i - 1040;
          off = row*130*64 + j*8;
        } else {
          int i2 = i - 2080;
          int strip = i2 >> 3;
          int r = 1 + (strip & 127);
          int side = strip >> 7;
          off = (r*130 + side*129)*64 + (i2 & 7)*8;
        }
        *reinterpret_cast<short8*>(base + off) = z;
      }
    } else {
      __hip_bfloat16* base = (kind == 1 ? pp : rp) + b*PPE;
      for (int i = t; i < 2064; i += 256) {
        int off;
        if (i < 1040) {
          int row = (i < 520) ? 0 : 129;
          int j = (i < 520) ? i : i - 520;
          off = row*130*32 + j*8;
        } else {
          int i2 = i - 1040;
          int strip = i2 >> 2;
          int r = 1 + (strip & 127);
          int side = strip >> 7;
          off = (r*130 + side*129)*32 + (i2 & 3)*8;
        }
        *reinterpret_cast<short8*>(base + off) = z;
      }
    }
  }
}

// ---------------------------------------------------------------------------
// K2: all-gates MFMA GEMM. R6: 64 px per block (2h x 32w, grid 1024) — each
// wall A-fragment feeds FOUR B-groups; wall L2 traffic 226->113 MB; 4-row
// window serves 2 output rows (staging bytes/px x0.7). LDS ~30KB.
// ---------------------------------------------------------------------------
__global__ __launch_bounds__(256)
void k_gates(const __hip_bfloat16* __restrict__ xpad,
             const __hip_bfloat16* __restrict__ popad,
             const __hip_bfloat16* __restrict__ wall,
             const float* __restrict__ po,
             const float* __restrict__ upd_b,
             const float* __restrict__ rst_b,
             const float* __restrict__ out_b,
             const float* __restrict__ wg_b,
             float* __restrict__ u_out,      // aliases out_mn
             float* __restrict__ cx_out,     // aliases out_off
             __hip_bfloat16* __restrict__ ropad,
             __hip_bfloat16* __restrict__ m_t) {
  __shared__ __align__(16) char winx[17408];   // [4][34][64] bf16
  __shared__ __align__(16) char winp[8704];    // [4][34][32] bf16
  __shared__ __align__(16) __hip_bfloat16 roL[64][32];
  int blk = blockIdx.x;
  int wtile = blk & 3;
  int hp = (blk >> 2) & 63;
  int b = blk >> 8;
  int h0 = hp * 2;
  int w0 = wtile * 32;
  int lane = threadIdx.x & 63;
  int wave = threadIdx.x >> 6;
  int t = threadIdx.x;

  #pragma unroll
  for (int j = 0; j < 4; ++j)
    ((unsigned int*)roL)[t + j*256] = 0u;

  const __hip_bfloat16* xpb = xpad + b * XPE;
  const __hip_bfloat16* ppb = popad + b * PPE;

  // stage x window: 1088 chunks (4 rows x 272), contiguous per row
  for (int i = t; i < 1088; i += 256) {
    int r = i / 272, cidx = i - r * 272;
    short8 v = *reinterpret_cast<const short8*>(
        xpb + ((h0 + r) * WP + w0) * Cc + cidx * 8);
    int o = i * 16;
    *reinterpret_cast<short8*>(winx + (o ^ (((o >> 7) & 7) << 4))) = v;
  }
  // stage po window: 544 chunks (4 rows x 136)
  for (int i = t; i < 544; i += 256) {
    int r = i / 136, cidx = i - r * 136;
    short8 v = *reinterpret_cast<const short8*>(
        ppb + ((h0 + r) * WP + w0) * 32 + cidx * 8);
    int o = i * 16;
    *reinterpret_cast<short8*>(winp + (o ^ (((o >> 6) & 3) << 4))) = v;
  }
  __syncthreads();

  int mrow = lane & 15;
  int quad = lane >> 4;
  int cotile = wave * 16;
  float4v ac[4];
  #pragma unroll
  for (int g = 0; g < 4; ++g) ac[g] = (float4v){0.f,0.f,0.f,0.f};

  #pragma unroll
  for (int ks = 0; ks < KT/32; ++ks) {
    short8 a = *reinterpret_cast<const short8*>(
        wall + (cotile + mrow) * KT + ks * 32 + quad * 8);
    if (ks < 18) {
      int n = ks >> 1;
      #pragma unroll
      for (int g = 0; g < 4; ++g) {
        int hh = g >> 1, pgi = g & 1;
        int rowidx = (n / 3 + hh) * 34 + pgi*16 + mrow + (n % 3);
        int lin = rowidx * 128 + (ks & 1) * 64 + quad * 16;
        short8 bf = *reinterpret_cast<const short8*>(
            winx + (lin ^ ((rowidx & 7) << 4)));
        ac[g] = __builtin_amdgcn_mfma_f32_16x16x32_bf16(a, bf, ac[g], 0, 0, 0);
      }
    } else {
      int n = ks - 18;
      #pragma unroll
      for (int g = 0; g < 4; ++g) {
        int hh = g >> 1, pgi = g & 1;
        int rowidx = (n / 3 + hh) * 34 + pgi*16 + mrow + (n % 3);
        int lin = rowidx * 64 + quad * 16;
        short8 bf = *reinterpret_cast<const short8*>(
            winp + (lin ^ ((rowidx & 3) << 4)));
        ac[g] = __builtin_amdgcn_mfma_f32_16x16x32_bf16(a, bf, ac[g], 0, 0, 0);
      }
    }
  }

  // epilogue: 4 groups (hh, pgi)
  float pvv[4][4];
  #pragma unroll
  for (int g = 0; g < 4; ++g) {
    int hh = g >> 1, pgi = g & 1;
    int sp = (h0 + hh) * Wd + w0 + pgi*16 + mrow;
    #pragma unroll
    for (int r = 0; r < 4; ++r) {
      int gr = cotile + quad * 4 + r;
      if (gr >= 18 && gr < 36)
        pvv[g][r] = po[(b*MHc + (gr-18))*HW + sp];
    }
  }
  #pragma unroll
  for (int g = 0; g < 4; ++g) {
    int hh = g >> 1, pgi = g & 1;
    int sp = (h0 + hh) * Wd + w0 + pgi*16 + mrow;
    #pragma unroll
    for (int r = 0; r < 4; ++r) {
      int gr = cotile + quad * 4 + r;
      float v = ac[g][r];
      if (gr < 18) {
        u_out[(b*MHc + gr)*HW + sp] = sigm(v + upd_b[gr]);
      } else if (gr < 36) {
        int oc = gr - 18;
        roL[hh*32 + pgi*16 + mrow][oc] = f2bf(sigm(v + rst_b[oc]) * pvv[g][r]);
      } else if (gr < 54) {
        int oc = gr - 36;
        cx_out[(b*MHc + oc)*HW + sp] = v + out_b[oc];
      } else if (gr < 63) {
        int nn = gr - 54;
        m_t[nn*(Bn*HW) + b*HW + sp] = f2bf(sigm(v + wg_b[nn]));
      }
    }
  }
  __syncthreads();
  // coalesced ropad store: two rows of 32px x 32ch
  #pragma unroll
  for (int hh = 0; hh < 2; ++hh) {
    unsigned int* dst = (unsigned int*)(ropad + b*PPE + ((h0+1+hh)*WP + (w0+1))*32);
    #pragma unroll
    for (int k = 0; k < 2; ++k)
      dst[t + k*256] = ((unsigned int*)roL)[hh*512 + t + k*256];
  }
}

// ---------------------------------------------------------------------------
// K3: fused stage-2 GEMM + offset/mean + deformable gather + warp GEMM.
// R6: (a) GEMM2 B-fragments read ropad DIRECTLY (coalesced; drops the ro-LDS
// staging + one barrier); (b) tap-split pipelined gather: taps 0-3 -> barrier
// -> {prefetch taps 4-8 || GEMM ks0-7} -> barrier -> GEMM ks8-17. Hides ~half
// the gather latency under the warp GEMM (T14 issue-early/write-late).
// ---------------------------------------------------------------------------
__global__ __launch_bounds__(512, 6)
void k_fuse(const __hip_bfloat16* __restrict__ xpad,
            const __hip_bfloat16* __restrict__ ropad,
            const __hip_bfloat16* __restrict__ w2,
            const __hip_bfloat16* __restrict__ wt,
            const __hip_bfloat16* __restrict__ m_t,
            const float* __restrict__ po,
            const float* __restrict__ mean,
            float* __restrict__ out_off,    // also cx_out (read then overwrite)
            float* __restrict__ out_mn,     // also u_out  (read then overwrite)
            float* __restrict__ out_x) {
  __shared__ __align__(16) __hip_bfloat16 xw[32][584];
  __shared__ float offL[32][18];
  __shared__ float mL[32][9];
  __shared__ __align__(16) float gw[288][4];
  __shared__ __align__(16) int   ga[288][2];

  int blk = blockIdx.x;
  int wtile = blk & 3;
  int h = (blk >> 2) & 127;
  int b = blk >> 9;
  int w0 = wtile * 32;
  int lane = threadIdx.x & 63;
  int wv = threadIdx.x >> 6;
  int t = threadIdx.x;
  int mrow = lane & 15;
  int quad = lane >> 4;

  // ---- phase 0: hoisted epilogue f32 loads (waves 0-3) + mL load ----
  float ov[4], uv[4], pv[4], mv[4];
  int gil[4];
  int am = wv & 1, pg = wv >> 1;     // valid for wv<4
  if (wv < 4) {
    int sp = h * Wd + w0 + pg*16 + mrow;
    #pragma unroll
    for (int r = 0; r < 4; ++r) {
      int gr = am*16 + quad * 4 + r;
      gil[r] = (b*MHc + gr)*HW + sp;
      if (gr < 18) {
        ov[r] = out_off[gil[r]];   // cx (aliased)
        uv[r] = out_mn[gil[r]];    // u  (aliased)
        pv[r] = po[gil[r]];
        mv[r] = mean[gil[r]];
      }
    }
  }
  if (t < 288) {
    int n = t >> 5, px = t & 31;
    mL[px][n] = bf2f(m_t[n*(Bn*HW) + b*HW + h*Wd + w0 + px]);
  }

  // ---- phase 2: waves 0-3 GEMM2 with DIRECT ropad B reads + epilogue ----
  if (wv < 4) {
    const __hip_bfloat16* rpb = ropad + b * PPE;
    float4v acc = {0.f, 0.f, 0.f, 0.f};
    #pragma unroll
    for (int ks = 0; ks < 9; ++ks) {
      short8 a = *reinterpret_cast<const short8*>(
          w2 + (am*16 + mrow) * KP + ks * 32 + quad * 8);
      short8 bfr = *reinterpret_cast<const short8*>(
          rpb + ((h + ks/3) * WP + w0 + pg*16 + mrow + ks%3) * 32 + quad * 8);
      acc = __builtin_amdgcn_mfma_f32_16x16x32_bf16(a, bfr, acc, 0, 0, 0);
    }
    #pragma unroll
    for (int r = 0; r < 4; ++r) {
      int gr = am*16 + quad * 4 + r;
      if (gr < 18) {
        float cand = tanhf(ov[r] + acc[r]);
        float mn = 0.5f * (mv[r] + pv[r]);
        float off = pv[r] * (1.f - uv[r]) + cand * uv[r] + mn;
        out_off[gil[r]] = off;
        out_mn[gil[r]]  = mn;
        offL[pg*16 + mrow][gr] = off;
      }
    }
  }
  __syncthreads();

  // ---- phase 3: bilinear weights/bases (288 tasks) ----
  if (t < 288) {
    int px = t / 9;
    int n = t - px * 9;
    int wp = w0 + px;
    float ox = offL[px][n];
    float oy = offL[px][9 + n];
    float mnv = mL[px][n];
    float px_ = (float)(h + 1) + (float)(n / 3 - 1) + ox;
    float py_ = (float)(wp + 1) + (float)(n % 3 - 1) + oy;
    float fx = floorf(px_), fy = floorf(py_);
    float xlt = fminf(fmaxf(fx,       0.f), 129.f);
    float ylt = fminf(fmaxf(fy,       0.f), 129.f);
    float xrb = fminf(fmaxf(fx + 1.f, 0.f), 129.f);
    float yrb = fminf(fmaxf(fy + 1.f, 0.f), 129.f);
    float pxc = fminf(fmaxf(px_, 0.f), 129.f);
    float pyc = fminf(fmaxf(py_, 0.f), 129.f);
    float glt = (1.f + xlt - pxc) * (1.f + ylt - pyc);
    float grb = (1.f - xrb + pxc) * (1.f - yrb + pyc);
    float glb = (1.f + xlt - pxc) * (1.f - yrb + pyc);
    float grt = (1.f - xrb + pxc) * (1.f + ylt - pyc);
    int ixl = (int)xlt, iyl = (int)ylt, ixr = (int)xrb, iyr = (int)yrb;
    bool yAdj = (iyr == iyl + 1);       // else iyr == iyl (clipped)
    gw[t][0] = (glt + (yAdj ? 0.f : glb)) * mnv;   // row ixl, col iyl
    gw[t][1] = (yAdj ? glb : 0.f) * mnv;           // row ixl, col iyl+1
    gw[t][2] = (grt + (yAdj ? 0.f : grb)) * mnv;   // row ixr, col iyl
    gw[t][3] = (yAdj ? grb : 0.f) * mnv;           // row ixr, col iyl+1
    ga[t][0] = (ixl * WP + iyl) * Cc;
    ga[t][1] = (ixr * WP + iyl) * Cc;
  }
  __syncthreads();

  // ---- phase 4a: gather taps 0-3 (1024 tasks) ----
  const __hip_bfloat16* xpb = xpad + b * XPE;
  #pragma unroll
  for (int rep = 0; rep < 2; ++rep) {
    int it = t + rep * 512;
    int qi = it >> 3, c0 = (it & 7) * 8;
    int px = qi >> 2, n = qi & 3;
    int q = px * 9 + n;
    float4v g = *reinterpret_cast<const float4v*>(gw[q]);
    int bL = ga[q][0] + c0, bR = ga[q][1] + c0;
    short8 l0 = *reinterpret_cast<const short8*>(xpb + bL);
    short8 l1 = *reinterpret_cast<const short8*>(xpb + bL + 64);
    short8 r0 = *reinterpret_cast<const short8*>(xpb + bR);
    short8 r1 = *reinterpret_cast<const short8*>(xpb + bR + 64);
    short8 ovv;
    #pragma unroll
    for (int j = 0; j < 8; ++j) {
      float vv = g.x * s2f(l0[j]);
      vv = fmaf(g.y, s2f(l1[j]), vv);
      vv = fmaf(g.z, s2f(r0[j]), vv);
      vv = fmaf(g.w, s2f(r1[j]), vv);
      ovv[j] = f2bs(vv);
    }
    *reinterpret_cast<short8*>(&xw[px][n * 64 + c0]) = ovv;
  }
  __syncthreads();

  // ---- phase 4b/5a: prefetch taps 4-8 interleaved with GEMM ks0-7 ----
  int ct = wv & 3, pg5 = wv >> 2;
  const __hip_bfloat16* wtw = wt + (ct*16 + mrow) * 576;
  int xrow = pg5*16 + mrow;
  float4v acc = {0.f, 0.f, 0.f, 0.f};

  // rep0 prefetch (tasks t): taps 4-8, 1280 tasks total
  int qi0 = t >> 3, c00 = (t & 7) * 8;
  int px0 = qi0 / 5, n0 = 4 + (qi0 - px0 * 5);
  int q0 = px0 * 9 + n0;
  float4v g0 = *reinterpret_cast<const float4v*>(gw[q0]);
  int bL0 = ga[q0][0] + c00, bR0 = ga[q0][1] + c00;
  short8 A00 = *reinterpret_cast<const short8*>(xpb + bL0);
  short8 A10 = *reinterpret_cast<const short8*>(xpb + bL0 + 64);
  short8 A20 = *reinterpret_cast<const short8*>(xpb + bR0);
  short8 A30 = *reinterpret_cast<const short8*>(xpb + bR0 + 64);

  // GEMM ks 0..3 (reads taps 0-3 only)
  #pragma unroll
  for (int ks = 0; ks < 4; ++ks) {
    short8 a = *reinterpret_cast<const short8*>(wtw + ks * 32 + quad * 8);
    short8 bfr = *reinterpret_cast<const short8*>(&xw[xrow][ks * 32 + quad * 8]);
    acc = __builtin_amdgcn_mfma_f32_16x16x32_bf16(a, bfr, acc, 0, 0, 0);
  }

  // convert + store rep0; prefetch rep1 (tasks t+512)
  {
    short8 ovv;
    #pragma unroll
    for (int j = 0; j < 8; ++j) {
      float vv = g0.x * s2f(A00[j]);
      vv = fmaf(g0.y, s2f(A10[j]), vv);
      vv = fmaf(g0.z, s2f(A20[j]), vv);
      vv = fmaf(g0.w, s2f(A30[j]), vv);
      ovv[j] = f2bs(vv);
    }
    *reinterpret_cast<short8*>(&xw[px0][n0 * 64 + c00]) = ovv;
  }
  int it1 = t + 512;
  int qi1 = it1 >> 3, c01 = (it1 & 7) * 8;
  int px1 = qi1 / 5, n1 = 4 + (qi1 - px1 * 5);
  int q1 = px1 * 9 + n1;
  float4v g1 = *reinterpret_cast<const float4v*>(gw[q1]);
  int bL1 = ga[q1][0] + c01, bR1 = ga[q1][1] + c01;
  short8 A01 = *reinterpret_cast<const short8*>(xpb + bL1);
  short8 A11 = *reinterpret_cast<const short8*>(xpb + bL1 + 64);
  short8 A21 = *reinterpret_cast<const short8*>(xpb + bR1);
  short8 A31 = *reinterpret_cast<const short8*>(xpb + bR1 + 64);

  // GEMM ks 4..5
  #pragma unroll
  for (int ks = 4; ks < 6; ++ks) {
    short8 a = *reinterpret_cast<const short8*>(wtw + ks * 32 + quad * 8);
    short8 bfr = *reinterpret_cast<const short8*>(&xw[xrow][ks * 32 + quad * 8]);
    acc = __builtin_amdgcn_mfma_f32_16x16x32_bf16(a, bfr, acc, 0, 0, 0);
  }

  // convert + store rep1; prefetch rep2 (tasks t+1024; valid t<256)
  {
    short8 ovv;
    #pragma unroll
    for (int j = 0; j < 8; ++j) {
      float vv = g1.x * s2f(A01[j]);
      vv = fmaf(g1.y, s2f(A11[j]), vv);
      vv = fmaf(g1.z, s2f(A21[j]), vv);
      vv = fmaf(g1.w, s2f(A31[j]), vv);
      ovv[j] = f2bs(vv);
    }
    *reinterpret_cast<short8*>(&xw[px1][n1 * 64 + c01]) = ovv;
  }
  bool ok2 = (t < 256);
  int it2 = t + 1024;
  int qi2 = it2 >> 3, c02 = (it2 & 7) * 8;
  int px2 = qi2 / 5, n2 = 4 + (qi2 - px2 * 5);
  int q2 = px2 * 9 + n2;
  float4v g2 = {0.f,0.f,0.f,0.f};
  short8 A02, A12, A22, A32;
  if (ok2) {
    g2 = *reinterpret_cast<const float4v*>(gw[q2]);
    int bL2 = ga[q2][0] + c02, bR2 = ga[q2][1] + c02;
    A02 = *reinterpret_cast<const short8*>(xpb + bL2);
    A12 = *reinterpret_cast<const short8*>(xpb + bL2 + 64);
    A22 = *reinterpret_cast<const short8*>(xpb + bR2);
    A32 = *reinterpret_cast<const short8*>(xpb + bR2 + 64);
  }

  // GEMM ks 6..7
  #pragma unroll
  for (int ks = 6; ks < 8; ++ks) {
    short8 a = *reinterpret_cast<const short8*>(wtw + ks * 32 + quad * 8);
    short8 bfr = *reinterpret_cast<const short8*>(&xw[xrow][ks * 32 + quad * 8]);
    acc = __builtin_amdgcn_mfma_f32_16x16x32_bf16(a, bfr, acc, 0, 0, 0);
  }

  // convert + store rep2
  if (ok2) {
    short8 ovv;
    #pragma unroll
    for (int j = 0; j < 8; ++j) {
      float vv = g2.x * s2f(A02[j]);
      vv = fmaf(g2.y, s2f(A12[j]), vv);
      vv = fmaf(g2.z, s2f(A22[j]), vv);
      vv = fmaf(g2.w, s2f(A32[j]), vv);
      ovv[j] = f2bs(vv);
    }
    *reinterpret_cast<short8*>(&xw[px2][n2 * 64 + c02]) = ovv;
  }
  __syncthreads();

  // ---- phase 5b: GEMM ks 8..17 (taps 4-8) + out write ----
  #pragma unroll
  for (int ks = 8; ks < 18; ++ks) {
    short8 a = *reinterpret_cast<const short8*>(wtw + ks * 32 + quad * 8);
    short8 bfr = *reinterpret_cast<const short8*>(&xw[xrow][ks * 32 + quad * 8]);
    acc = __builtin_amdgcn_mfma_f32_16x16x32_bf16(a, bfr, acc, 0, 0, 0);
  }
  #pragma unroll
  for (int r = 0; r < 4; ++r) {
    int co = ct*16 + quad * 4 + r;
    out_x[((b * Cc + co) * Hh + h) * Wd + w0 + pg5*16 + mrow] = acc[r];
  }
}

// ---------------------------------------------------------------------------
// Fallback (R9-verified scalar pipeline; zero ws)
// ---------------------------------------------------------------------------
__global__ void f_convAB(const float* __restrict__ x, const float* __restrict__ po,
                         const float* __restrict__ wA, const float* __restrict__ bA,
                         const float* __restrict__ wB, const float* __restrict__ bB,
                         float* __restrict__ u_scr, float* __restrict__ ro_scr) {
  int idx = blockIdx.x * 256 + threadIdx.x;
  if (idx >= Bn * MHc * HW) return;
  int w = idx & 127, h = (idx >> 7) & 127, oc = (idx >> 14) % MHc, b = idx / (MHc*HW);
  float accA = bA[oc], accB = bB[oc];
  const float* xb = x + b*Cc*HW; const float* pb = po + b*MHc*HW;
  for (int ic = 0; ic < Cc + MHc; ++ic) {
    const float* src = (ic < Cc) ? (xb + ic*HW) : (pb + (ic-Cc)*HW);
    const float* wa = wA + (oc*(Cc+MHc)+ic)*9; const float* wb = wB + (oc*(Cc+MHc)+ic)*9;
    for (int kh = 0; kh < 3; ++kh) { int hh = h+kh-1; if ((unsigned)hh >= Hh) continue;
      for (int kw = 0; kw < 3; ++kw) { int ww = w+kw-1; if ((unsigned)ww >= Wd) continue;
        float v = src[hh*Wd+ww]; accA += v*wa[kh*3+kw]; accB += v*wb[kh*3+kw]; } }
  }
  u_scr[idx] = sigm(accA); ro_scr[idx] = sigm(accB) * pb[oc*HW + h*Wd + w];
}
__global__ void f_convC(const float* __restrict__ x, const float* __restrict__ po,
                        const float* __restrict__ mean, const float* __restrict__ wC,
                        const float* __restrict__ bC, const float* __restrict__ u_scr,
                        const float* __restrict__ ro_scr, float* __restrict__ out_off,
                        float* __restrict__ out_mean) {
  int idx = blockIdx.x * 256 + threadIdx.x;
  if (idx >= Bn * MHc * HW) return;
  int w = idx & 127, h = (idx >> 7) & 127, oc = (idx >> 14) % MHc, b = idx / (MHc*HW);
  float acc = bC[oc];
  const float* xb = x + b*Cc*HW; const float* rb = ro_scr + b*MHc*HW;
  for (int ic = 0; ic < Cc + MHc; ++ic) {
    const float* src = (ic < Cc) ? (xb + ic*HW) : (rb + (ic-Cc)*HW);
    const float* wv = wC + (oc*(Cc+MHc)+ic)*9;
    for (int kh = 0; kh < 3; ++kh) { int hh = h+kh-1; if ((unsigned)hh >= Hh) continue;
      for (int kw = 0; kw < 3; ++kw) { int ww = w+kw-1; if ((unsigned)ww >= Wd) continue;
        acc += src[hh*Wd+ww]*wv[kh*3+kw]; } }
  }
  float cand = tanhf(acc); float u = u_scr[idx]; float p = po[idx];
  float mn = 0.5f*(mean[idx]+p);
  out_off[idx] = p*(1.f-u)+cand*u+mn; out_mean[idx] = mn;
}
__global__ __launch_bounds__(256)
void f_warp(const float* __restrict__ x, const float* __restrict__ off_f,
            const float* __restrict__ wg, const float* __restrict__ bg,
            const float* __restrict__ wc, float* __restrict__ out) {
  __shared__ float mred[4][Np][64]; __shared__ float mval[4][Np];
  __shared__ float xwv[4][Np][64];
  int lane = threadIdx.x & 63, wave = threadIdx.x >> 6;
  int p = blockIdx.x * 4 + wave;
  int b = p >> 14, rem = p & 16383, h = rem >> 7, w = rem & 127;
  const float* xc = x + (b*Cc + lane)*HW;
  float part[Np];
  for (int n = 0; n < Np; ++n) part[n] = 0.f;
  for (int kh = 0; kh < 3; ++kh) { int hh = h+kh-1; if ((unsigned)hh >= Hh) continue;
    for (int kw = 0; kw < 3; ++kw) { int ww = w+kw-1; if ((unsigned)ww >= Wd) continue;
      float v = xc[hh*Wd+ww];
      for (int n = 0; n < Np; ++n) part[n] += v*wg[(n*Cc+lane)*9+kh*3+kw]; } }
  for (int n = 0; n < Np; ++n) mred[wave][n][lane] = part[n];
  __syncthreads();
  if (lane < Np) { float s = bg[lane];
    for (int c = 0; c < Cc; ++c) s += mred[wave][lane][c];
    mval[wave][lane] = sigm(s); }
  __syncthreads();
  const float* offb = off_f + b*MHc*HW; int sp = h*Wd + w;
  for (int n = 0; n < Np; ++n) {
    float px = (float)(h+1) + (float)(n/3-1) + offb[n*HW+sp];
    float py = (float)(w+1) + (float)(n%3-1) + offb[(9+n)*HW+sp];
    float fxq = floorf(px), fyq = floorf(py);
    float xlt = fminf(fmaxf(fxq,0.f),129.f), ylt = fminf(fmaxf(fyq,0.f),129.f);
    float xrb = fminf(fmaxf(fxq+1.f,0.f),129.f), yrb = fminf(fmaxf(fyq+1.f,0.f),129.f);
    float pxc = fminf(fmaxf(px,0.f),129.f), pyc = fminf(fmaxf(py,0.f),129.f);
    float glt = (1.f+xlt-pxc)*(1.f+ylt-pyc), grb = (1.f-xrb+pxc)*(1.f-yrb+pyc);
    float glb = (1.f+xlt-pxc)*(1.f-yrb+pyc), grt = (1.f-xrb+pxc)*(1.f+ylt-pyc);
    int ixl=(int)xlt, iyl=(int)ylt, ixr=(int)xrb, iyr=(int)yrb;
    float vlt=0.f,vrb=0.f,vlb=0.f,vrt=0.f;
    if (ixl>=1&&ixl<=Hh&&iyl>=1&&iyl<=Wd) vlt = xc[(ixl-1)*Wd+(iyl-1)];
    if (ixr>=1&&ixr<=Hh&&iyr>=1&&iyr<=Wd) vrb = xc[(ixr-1)*Wd+(iyr-1)];
    if (ixl>=1&&ixl<=Hh&&iyr>=1&&iyr<=Wd) vlb = xc[(ixl-1)*Wd+(iyr-1)];
    if (ixr>=1&&ixr<=Hh&&iyl>=1&&iyl<=Wd) vrt = xc[(ixr-1)*Wd+(iyl-1)];
    xwv[wave][n][lane] = (glt*vlt+grb*vrb+glb*vlb+grt*vrt)*mval[wave][n];
  }
  __syncthreads();
  float acc = 0.f;
  for (int c = 0; c < Cc; ++c)
    for (int n = 0; n < Np; ++n)
      acc += xwv[wave][n][c]*wc[(lane*Cc+c)*9+n];
  out[(b*Cc+lane)*HW + h*Wd + w] = acc;
}

// ---------------------------------------------------------------------------
extern "C" void kernel_launch(void* const* d_in, const int* in_sizes, int n_in,
                              void* d_out, int out_size, void* d_ws, size_t ws_size,
                              hipStream_t stream) {
  (void)in_sizes; (void)n_in; (void)out_size;
  const float* x_t   = (const float*)d_in[0];
  const float* po    = (const float*)d_in[1];
  const float* mean  = (const float*)d_in[2];
  const float* upd_w = (const float*)d_in[3];
  const float* upd_b = (const float*)d_in[4];
  const float* rst_w = (const float*)d_in[5];
  const float* rst_b = (const float*)d_in[6];
  const float* out_w = (const float*)d_in[7];
  const float* out_b = (const float*)d_in[8];
  const float* wg_w  = (const float*)d_in[9];
  const float* wg_b  = (const float*)d_in[10];
  const float* wcw   = (const float*)d_in[11];

  float* out_x   = (float*)d_out;            // [4,64,128,128]
  float* out_off = out_x + 4194304;          // [4,18,128,128]
  float* out_mn  = out_off + 1179648;        // [4,18,128,128]

  char* ws = (char*)d_ws;
  __hip_bfloat16* xpad  = (__hip_bfloat16*)(ws + 0);          //  8,652,800
  __hip_bfloat16* popad = (__hip_bfloat16*)(ws + 8652800);    //  4,326,400
  __hip_bfloat16* ropad = (__hip_bfloat16*)(ws + 12979200);   //  4,326,400
  __hip_bfloat16* wall  = (__hip_bfloat16*)(ws + 17305600);   //    110,592
  __hip_bfloat16* w2    = (__hip_bfloat16*)(ws + 17416192);   //     18,432
  __hip_bfloat16* wt_bf = (__hip_bfloat16*)(ws + 17434624);   //     73,728
  __hip_bfloat16* m_t   = (__hip_bfloat16*)(ws + 17508352);   //  1,179,648
  const size_t WS_NEED = 18688000;

  if (ws_size >= WS_NEED) {
    // no memset: pad borders zeroed by k_prep's border blocks; all other ws
    // regions are fully written before being read.
    hipLaunchKernelGGL(k_prep,  dim3(1432), dim3(256), 0, stream,
                       x_t, po, upd_w, rst_w, out_w, wg_w, wcw,
                       xpad, popad, ropad, wall, w2, wt_bf);
    // u -> out_mn region, cx -> out_off region (exact [B,18,HW] aliases;
    // k_fuse reads each address before overwriting it)
    hipLaunchKernelGGL(k_gates, dim3(1024), dim3(256), 0, stream,
                       xpad, popad, wall, po, upd_b, rst_b, out_b, wg_b,
                       out_mn, out_off, ropad, m_t);
    hipLaunchKernelGGL(k_fuse,  dim3(2048), dim3(512), 0, stream,
                       xpad, ropad, w2, wt_bf, m_t, po, mean,
                       out_off, out_mn, out_x);
  } else {
    float* u_scr  = out_x;
    float* cx_scr = out_x + 1179648;
    hipLaunchKernelGGL(f_convAB, dim3(4608), dim3(256), 0, stream,
                       x_t, po, upd_w, upd_b, rst_w, rst_b, u_scr, cx_scr);
    hipLaunchKernelGGL(f_convC,  dim3(4608), dim3(256), 0, stream,
                       x_t, po, mean, out_w, out_b, u_scr, cx_scr,
                       out_off, out_mn);
    hipLaunchKernelGGL(f_warp,   dim3(16384), dim3(256), 0, stream,
                       x_t, out_off, wg_w, wg_b, wcw, out_x);
  }
}

// Round 7
// 176.434 us; speedup vs baseline: 1.0431x; 1.0431x over previous
//
#include <hip/hip_runtime.h>
#include <hip/hip_bf16.h>
#include <math.h>

// Problem constants
#define Bn  4
#define Cc  64
#define MHc 18
#define Hh  128
#define Wd  128
#define HW  (Hh*Wd)
#define Np  9
#define HP  130
#define WP  130
#define XPE (HP*WP*Cc)     // xpad elems per batch (bf16): 1,081,600
#define PPE (HP*WP*32)     // popad/ropad elems per batch: 540,800
#define KX  576            // x-tap K (9*64)
#define KP  288            // po-tap K (9*32)
#define KT  (KX+KP)        // 864 total K, 27 MFMA steps

typedef __attribute__((ext_vector_type(8))) short short8;
typedef __attribute__((ext_vector_type(4))) float float4v;

__device__ __forceinline__ float bf2f(__hip_bfloat16 x) { return __bfloat162float(x); }
__device__ __forceinline__ __hip_bfloat16 f2bf(float x) { return __float2bfloat16(x); }
__device__ __forceinline__ float sigm(float x) { return 1.f / (1.f + expf(-x)); }
__device__ __forceinline__ float s2f(short s) {            // bf16 bits -> f32
  return __uint_as_float(((unsigned)(unsigned short)s) << 16);
}
__device__ __forceinline__ short f2bs(float x) {           // f32 -> bf16 bits (RNE)
  __hip_bfloat16 h = __float2bfloat16(x);
  return *reinterpret_cast<short*>(&h);
}

#define NW1 (64*KT)          // 55296
#define NW2 (32*KP)          // 9216
#define NW3 (Cc*Cc*Np)       // 36864  (total 101376 = 396*256)

// ---------------------------------------------------------------------------
// K1: prep. blk<512: x row-block | 512..1023: popad row (LDS stage, writes
// ALL 32 ch incl. zeros for 18..31 — required, weights are zero but NaN
// garbage would poison MFMA) | 1024..1419: weights | 1420..1431: borders.
// ---------------------------------------------------------------------------
__global__ __launch_bounds__(256)
void k_prep(const float* __restrict__ x, const float* __restrict__ po,
            const float* __restrict__ upd_w, const float* __restrict__ rst_w,
            const float* __restrict__ out_w, const float* __restrict__ wg_w,
            const float* __restrict__ wcw,
            __hip_bfloat16* __restrict__ xp, __hip_bfloat16* __restrict__ pp,
            __hip_bfloat16* __restrict__ rp,
            __hip_bfloat16* __restrict__ wall, __hip_bfloat16* __restrict__ w2,
            __hip_bfloat16* __restrict__ wt) {
  __shared__ float tile[128][65];
  int blk = blockIdx.x;
  int t = threadIdx.x;
  if (blk < 512) {
    int b = blk >> 7, h = blk & 127;
    int c = t >> 2;
    int wbase = (t & 3) * 32;
    const float* src = &x[(b*Cc + c)*HW + h*Wd + wbase];
    #pragma unroll
    for (int j = 0; j < 8; ++j) {
      float4v v = *reinterpret_cast<const float4v*>(src + j*4);
      tile[wbase + j*4 + 0][c] = v.x;
      tile[wbase + j*4 + 1][c] = v.y;
      tile[wbase + j*4 + 2][c] = v.z;
      tile[wbase + j*4 + 3][c] = v.w;
    }
    __syncthreads();
    #pragma unroll
    for (int j = 0; j < 4; ++j) {
      int i = t + j * 256;
      int px = i >> 3, oct = i & 7;
      short8 ov;
      #pragma unroll
      for (int e = 0; e < 8; ++e) ov[e] = f2bs(tile[px][oct*8 + e]);
      *reinterpret_cast<short8*>(
          &xp[b*XPE + ((h+1)*WP + px + 1)*Cc + oct*8]) = ov;
    }
  } else if (blk < 1024) {
    int pb = blk - 512;             // b*128 + h
    int h = pb & 127;
    int b = pb >> 7;
    __hip_bfloat16* pt = (__hip_bfloat16*)&tile[0][0];   // [128][32] bf16, 8KB
    int w = t & 127;
    int half = t >> 7;
    float v[9];
    #pragma unroll
    for (int j = 0; j < 9; ++j)
      v[j] = po[(b*MHc + half*9 + j)*HW + h*Wd + w];
    #pragma unroll
    for (int j = 0; j < 9; ++j)
      pt[w*32 + half*9 + j] = f2bf(v[j]);
    // zero ch 18..31 (1792 elems)
    for (int i = t; i < 128*14; i += 256) {
      int px = i / 14, ch = 18 + i % 14;
      pt[px*32 + ch] = f2bf(0.f);
    }
    __syncthreads();
    // coalesced stores: 512 short8 chunks, 2 per thread
    #pragma unroll
    for (int k = 0; k < 2; ++k) {
      int i = t + k*256;
      int px = i >> 2, oct = i & 3;
      short8 val = *reinterpret_cast<const short8*>(pt + px*32 + oct*8);
      *reinterpret_cast<short8*>(
          &pp[b*PPE + ((h+1)*WP + (px+1))*32 + oct*8]) = val;
    }
  } else if (blk < 1420) {
    int idx = (blk - 1024) * 256 + t;
    if (idx < NW1) {
      int k  = idx % KT;
      int gr = idx / KT;
      float v = 0.f;
      if (k < KX) {
        int n = k >> 6, ci = k & 63;
        if      (gr < 18) v = upd_w[(gr*(Cc+MHc) + ci)*9 + n];
        else if (gr < 36) v = rst_w[((gr-18)*(Cc+MHc) + ci)*9 + n];
        else if (gr < 54) v = out_w[((gr-36)*(Cc+MHc) + ci)*9 + n];
        else if (gr < 63) v = wg_w[((gr-54)*Cc + ci)*9 + n];
      } else {
        int kk = k - KX;
        int n = kk >> 5, jc = kk & 31;
        if (jc < 18) {
          if      (gr < 18) v = upd_w[(gr*(Cc+MHc) + Cc + jc)*9 + n];
          else if (gr < 36) v = rst_w[((gr-18)*(Cc+MHc) + Cc + jc)*9 + n];
        }
      }
      wall[idx] = f2bf(v);
    } else if (idx < NW1 + NW2) {
      int i2 = idx - NW1;
      int k  = i2 % KP;
      int oc = i2 / KP;
      int n = k >> 5, jc = k & 31;
      float v = (oc < 18 && jc < 18) ? out_w[(oc*(Cc+MHc) + Cc + jc)*9 + n] : 0.f;
      w2[i2] = f2bf(v);
    } else if (idx < NW1 + NW2 + NW3) {
      int i3 = idx - NW1 - NW2;
      int k  = i3 % 576;
      int co = i3 / 576;
      wt[i3] = f2bf(wcw[(co*Cc + (k & 63))*9 + (k >> 6)]);
    }
  } else {
    // border zero: bid 0..11 -> kind(4 blocks each): xpad / popad / ropad
    int bid = blk - 1420;
    int kind = bid >> 2;
    int b = bid & 3;
    short8 z = {0,0,0,0,0,0,0,0};
    if (kind == 0) {
      __hip_bfloat16* base = xp + b*XPE;
      for (int i = t; i < 4128; i += 256) {
        int off;
        if (i < 2080) {
          int row = (i < 1040) ? 0 : 129;
          int j = (i < 1040) ? i : i - 1040;
          off = row*130*64 + j*8;
        } else {
          int i2 = i - 2080;
          int strip = i2 >> 3;
          int r = 1 + (strip & 127);
          int side = strip >> 7;
          off = (r*130 + side*129)*64 + (i2 & 7)*8;
        }
        *reinterpret_cast<short8*>(base + off) = z;
      }
    } else {
      __hip_bfloat16* base = (kind == 1 ? pp : rp) + b*PPE;
      for (int i = t; i < 2064; i += 256) {
        int off;
        if (i < 1040) {
          int row = (i < 520) ? 0 : 129;
          int j = (i < 520) ? i : i - 520;
          off = row*130*32 + j*8;
        } else {
          int i2 = i - 1040;
          int strip = i2 >> 2;
          int r = 1 + (strip & 127);
          int side = strip >> 7;
          off = (r*130 + side*129)*32 + (i2 & 3)*8;
        }
        *reinterpret_cast<short8*>(base + off) = z;
      }
    }
  }
}

// ---------------------------------------------------------------------------
// K2: all-gates MFMA GEMM. 32 px per block (grid 2048) — R4/R5-proven config
// (64px regressed: occupancy loss > traffic win, R6 measured).
// ---------------------------------------------------------------------------
__global__ __launch_bounds__(256)
void k_gates(const __hip_bfloat16* __restrict__ xpad,
             const __hip_bfloat16* __restrict__ popad,
             const __hip_bfloat16* __restrict__ wall,
             const float* __restrict__ po,
             const float* __restrict__ upd_b,
             const float* __restrict__ rst_b,
             const float* __restrict__ out_b,
             const float* __restrict__ wg_b,
             float* __restrict__ u_out,      // aliases out_mn
             float* __restrict__ cx_out,     // aliases out_off
             __hip_bfloat16* __restrict__ ropad,
             __hip_bfloat16* __restrict__ m_t) {
  __shared__ __align__(16) char winx[13056];
  __shared__ __align__(16) char winp[6528];
  __shared__ __align__(16) __hip_bfloat16 roL[32][32];
  int blk = blockIdx.x;
  int wtile = blk & 3;
  int h = (blk >> 2) & 127;
  int b = blk >> 9;
  int w0 = wtile * 32;
  int lane = threadIdx.x & 63;
  int wave = threadIdx.x >> 6;
  int t = threadIdx.x;

  ((unsigned int*)roL)[t] = 0u;
  ((unsigned int*)roL)[t + 256] = 0u;

  const __hip_bfloat16* xpb = xpad + b * XPE;
  const __hip_bfloat16* ppb = popad + b * PPE;

  for (int i = t; i < 816; i += 256) {
    int r = i / 272, cidx = i - r * 272;
    short8 v = *reinterpret_cast<const short8*>(
        xpb + ((h + r) * WP + w0) * Cc + cidx * 8);
    int o = i * 16;
    *reinterpret_cast<short8*>(winx + (o ^ (((o >> 7) & 7) << 4))) = v;
  }
  for (int i = t; i < 408; i += 256) {
    int r = i / 136, cidx = i - r * 136;
    short8 v = *reinterpret_cast<const short8*>(
        ppb + ((h + r) * WP + w0) * 32 + cidx * 8);
    int o = i * 16;
    *reinterpret_cast<short8*>(winp + (o ^ (((o >> 6) & 3) << 4))) = v;
  }
  __syncthreads();

  int mrow = lane & 15;
  int quad = lane >> 4;
  int cotile = wave * 16;
  float4v acc0 = {0.f, 0.f, 0.f, 0.f};
  float4v acc1 = {0.f, 0.f, 0.f, 0.f};
  #pragma unroll
  for (int ks = 0; ks < KT/32; ++ks) {
    short8 a = *reinterpret_cast<const short8*>(
        wall + (cotile + mrow) * KT + ks * 32 + quad * 8);
    short8 b0, b1;
    if (ks < 18) {
      int n = ks >> 1;
      int r0i = (n / 3) * 34 + mrow + (n % 3);
      int r1i = r0i + 16;
      int l0 = r0i * 128 + (ks & 1) * 64 + quad * 16;
      int l1 = r1i * 128 + (ks & 1) * 64 + quad * 16;
      b0 = *reinterpret_cast<const short8*>(winx + (l0 ^ ((r0i & 7) << 4)));
      b1 = *reinterpret_cast<const short8*>(winx + (l1 ^ ((r1i & 7) << 4)));
    } else {
      int n = ks - 18;
      int r0i = (n / 3) * 34 + mrow + (n % 3);
      int r1i = r0i + 16;
      int l0 = r0i * 64 + quad * 16;
      int l1 = r1i * 64 + quad * 16;
      b0 = *reinterpret_cast<const short8*>(winp + (l0 ^ ((r0i & 3) << 4)));
      b1 = *reinterpret_cast<const short8*>(winp + (l1 ^ ((r1i & 3) << 4)));
    }
    acc0 = __builtin_amdgcn_mfma_f32_16x16x32_bf16(a, b0, acc0, 0, 0, 0);
    acc1 = __builtin_amdgcn_mfma_f32_16x16x32_bf16(a, b1, acc1, 0, 0, 0);
  }

  int sp0 = h * Wd + w0 + mrow;
  int sp1 = sp0 + 16;
  float pv0[4], pv1[4];
  #pragma unroll
  for (int r = 0; r < 4; ++r) {
    int gr = cotile + quad * 4 + r;
    if (gr >= 18 && gr < 36) {
      pv0[r] = po[(b*MHc + (gr-18))*HW + sp0];
      pv1[r] = po[(b*MHc + (gr-18))*HW + sp1];
    }
  }
  #pragma unroll
  for (int r = 0; r < 4; ++r) {
    int gr = cotile + quad * 4 + r;
    float v0 = acc0[r], v1 = acc1[r];
    if (gr < 18) {
      u_out[(b*MHc + gr)*HW + sp0] = sigm(v0 + upd_b[gr]);
      u_out[(b*MHc + gr)*HW + sp1] = sigm(v1 + upd_b[gr]);
    } else if (gr < 36) {
      int oc = gr - 18;
      roL[mrow][oc]      = f2bf(sigm(v0 + rst_b[oc]) * pv0[r]);
      roL[16 + mrow][oc] = f2bf(sigm(v1 + rst_b[oc]) * pv1[r]);
    } else if (gr < 54) {
      int oc = gr - 36;
      cx_out[(b*MHc + oc)*HW + sp0] = v0 + out_b[oc];
      cx_out[(b*MHc + oc)*HW + sp1] = v1 + out_b[oc];
    } else if (gr < 63) {
      int nn = gr - 54;
      m_t[nn*(Bn*HW) + b*HW + sp0] = f2bf(sigm(v0 + wg_b[nn]));
      m_t[nn*(Bn*HW) + b*HW + sp1] = f2bf(sigm(v1 + wg_b[nn]));
    }
  }
  __syncthreads();
  unsigned int* dst = (unsigned int*)(ropad + b*PPE + ((h+1)*WP + (w0+1))*32);
  dst[t] = ((unsigned int*)roL)[t];
  dst[t + 256] = ((unsigned int*)roL)[t + 256];
}

// ---------------------------------------------------------------------------
// K3: fused stage-2 GEMM + offset/mean + deformable gather + warp GEMM.
// R6-proven: direct ropad GEMM2 B-reads + tap-split pipelined gather.
// ---------------------------------------------------------------------------
__global__ __launch_bounds__(512, 6)
void k_fuse(const __hip_bfloat16* __restrict__ xpad,
            const __hip_bfloat16* __restrict__ ropad,
            const __hip_bfloat16* __restrict__ w2,
            const __hip_bfloat16* __restrict__ wt,
            const __hip_bfloat16* __restrict__ m_t,
            const float* __restrict__ po,
            const float* __restrict__ mean,
            float* __restrict__ out_off,    // also cx_out (read then overwrite)
            float* __restrict__ out_mn,     // also u_out  (read then overwrite)
            float* __restrict__ out_x) {
  __shared__ __align__(16) __hip_bfloat16 xw[32][584];
  __shared__ float offL[32][18];
  __shared__ float mL[32][9];
  __shared__ __align__(16) float gw[288][4];
  __shared__ __align__(16) int   ga[288][2];

  int blk = blockIdx.x;
  int wtile = blk & 3;
  int h = (blk >> 2) & 127;
  int b = blk >> 9;
  int w0 = wtile * 32;
  int lane = threadIdx.x & 63;
  int wv = threadIdx.x >> 6;
  int t = threadIdx.x;
  int mrow = lane & 15;
  int quad = lane >> 4;

  // ---- phase 0: hoisted epilogue f32 loads (waves 0-3) + mL load ----
  float ov[4], uv[4], pv[4], mv[4];
  int gil[4];
  int am = wv & 1, pg = wv >> 1;     // valid for wv<4
  if (wv < 4) {
    int sp = h * Wd + w0 + pg*16 + mrow;
    #pragma unroll
    for (int r = 0; r < 4; ++r) {
      int gr = am*16 + quad * 4 + r;
      gil[r] = (b*MHc + gr)*HW + sp;
      if (gr < 18) {
        ov[r] = out_off[gil[r]];   // cx (aliased)
        uv[r] = out_mn[gil[r]];    // u  (aliased)
        pv[r] = po[gil[r]];
        mv[r] = mean[gil[r]];
      }
    }
  }
  if (t < 288) {
    int n = t >> 5, px = t & 31;
    mL[px][n] = bf2f(m_t[n*(Bn*HW) + b*HW + h*Wd + w0 + px]);
  }

  // ---- phase 2: waves 0-3 GEMM2 with DIRECT ropad B reads + epilogue ----
  if (wv < 4) {
    const __hip_bfloat16* rpb = ropad + b * PPE;
    float4v acc = {0.f, 0.f, 0.f, 0.f};
    #pragma unroll
    for (int ks = 0; ks < 9; ++ks) {
      short8 a = *reinterpret_cast<const short8*>(
          w2 + (am*16 + mrow) * KP + ks * 32 + quad * 8);
      short8 bfr = *reinterpret_cast<const short8*>(
          rpb + ((h + ks/3) * WP + w0 + pg*16 + mrow + ks%3) * 32 + quad * 8);
      acc = __builtin_amdgcn_mfma_f32_16x16x32_bf16(a, bfr, acc, 0, 0, 0);
    }
    #pragma unroll
    for (int r = 0; r < 4; ++r) {
      int gr = am*16 + quad * 4 + r;
      if (gr < 18) {
        float cand = tanhf(ov[r] + acc[r]);
        float mn = 0.5f * (mv[r] + pv[r]);
        float off = pv[r] * (1.f - uv[r]) + cand * uv[r] + mn;
        out_off[gil[r]] = off;
        out_mn[gil[r]]  = mn;
        offL[pg*16 + mrow][gr] = off;
      }
    }
  }
  __syncthreads();

  // ---- phase 3: bilinear weights/bases (288 tasks) ----
  if (t < 288) {
    int px = t / 9;
    int n = t - px * 9;
    int wp = w0 + px;
    float ox = offL[px][n];
    float oy = offL[px][9 + n];
    float mnv = mL[px][n];
    float px_ = (float)(h + 1) + (float)(n / 3 - 1) + ox;
    float py_ = (float)(wp + 1) + (float)(n % 3 - 1) + oy;
    float fx = floorf(px_), fy = floorf(py_);
    float xlt = fminf(fmaxf(fx,       0.f), 129.f);
    float ylt = fminf(fmaxf(fy,       0.f), 129.f);
    float xrb = fminf(fmaxf(fx + 1.f, 0.f), 129.f);
    float yrb = fminf(fmaxf(fy + 1.f, 0.f), 129.f);
    float pxc = fminf(fmaxf(px_, 0.f), 129.f);
    float pyc = fminf(fmaxf(py_, 0.f), 129.f);
    float glt = (1.f + xlt - pxc) * (1.f + ylt - pyc);
    float grb = (1.f - xrb + pxc) * (1.f - yrb + pyc);
    float glb = (1.f + xlt - pxc) * (1.f - yrb + pyc);
    float grt = (1.f - xrb + pxc) * (1.f + ylt - pyc);
    int ixl = (int)xlt, iyl = (int)ylt, ixr = (int)xrb, iyr = (int)yrb;
    bool yAdj = (iyr == iyl + 1);       // else iyr == iyl (clipped)
    gw[t][0] = (glt + (yAdj ? 0.f : glb)) * mnv;   // row ixl, col iyl
    gw[t][1] = (yAdj ? glb : 0.f) * mnv;           // row ixl, col iyl+1
    gw[t][2] = (grt + (yAdj ? 0.f : grb)) * mnv;   // row ixr, col iyl
    gw[t][3] = (yAdj ? grb : 0.f) * mnv;           // row ixr, col iyl+1
    ga[t][0] = (ixl * WP + iyl) * Cc;
    ga[t][1] = (ixr * WP + iyl) * Cc;
  }
  __syncthreads();

  // ---- phase 4a: gather taps 0-3 (1024 tasks) ----
  const __hip_bfloat16* xpb = xpad + b * XPE;
  #pragma unroll
  for (int rep = 0; rep < 2; ++rep) {
    int it = t + rep * 512;
    int qi = it >> 3, c0 = (it & 7) * 8;
    int px = qi >> 2, n = qi & 3;
    int q = px * 9 + n;
    float4v g = *reinterpret_cast<const float4v*>(gw[q]);
    int bL = ga[q][0] + c0, bR = ga[q][1] + c0;
    short8 l0 = *reinterpret_cast<const short8*>(xpb + bL);
    short8 l1 = *reinterpret_cast<const short8*>(xpb + bL + 64);
    short8 r0 = *reinterpret_cast<const short8*>(xpb + bR);
    short8 r1 = *reinterpret_cast<const short8*>(xpb + bR + 64);
    short8 ovv;
    #pragma unroll
    for (int j = 0; j < 8; ++j) {
      float vv = g.x * s2f(l0[j]);
      vv = fmaf(g.y, s2f(l1[j]), vv);
      vv = fmaf(g.z, s2f(r0[j]), vv);
      vv = fmaf(g.w, s2f(r1[j]), vv);
      ovv[j] = f2bs(vv);
    }
    *reinterpret_cast<short8*>(&xw[px][n * 64 + c0]) = ovv;
  }
  __syncthreads();

  // ---- phase 4b/5a: prefetch taps 4-8 interleaved with GEMM ks0-7 ----
  int ct = wv & 3, pg5 = wv >> 2;
  const __hip_bfloat16* wtw = wt + (ct*16 + mrow) * 576;
  int xrow = pg5*16 + mrow;
  float4v acc = {0.f, 0.f, 0.f, 0.f};

  // rep0 prefetch (tasks t): taps 4-8, 1280 tasks total
  int qi0 = t >> 3, c00 = (t & 7) * 8;
  int px0 = qi0 / 5, n0 = 4 + (qi0 - px0 * 5);
  int q0 = px0 * 9 + n0;
  float4v g0 = *reinterpret_cast<const float4v*>(gw[q0]);
  int bL0 = ga[q0][0] + c00, bR0 = ga[q0][1] + c00;
  short8 A00 = *reinterpret_cast<const short8*>(xpb + bL0);
  short8 A10 = *reinterpret_cast<const short8*>(xpb + bL0 + 64);
  short8 A20 = *reinterpret_cast<const short8*>(xpb + bR0);
  short8 A30 = *reinterpret_cast<const short8*>(xpb + bR0 + 64);

  // GEMM ks 0..3 (reads taps 0-3 only)
  #pragma unroll
  for (int ks = 0; ks < 4; ++ks) {
    short8 a = *reinterpret_cast<const short8*>(wtw + ks * 32 + quad * 8);
    short8 bfr = *reinterpret_cast<const short8*>(&xw[xrow][ks * 32 + quad * 8]);
    acc = __builtin_amdgcn_mfma_f32_16x16x32_bf16(a, bfr, acc, 0, 0, 0);
  }

  // convert + store rep0; prefetch rep1 (tasks t+512)
  {
    short8 ovv;
    #pragma unroll
    for (int j = 0; j < 8; ++j) {
      float vv = g0.x * s2f(A00[j]);
      vv = fmaf(g0.y, s2f(A10[j]), vv);
      vv = fmaf(g0.z, s2f(A20[j]), vv);
      vv = fmaf(g0.w, s2f(A30[j]), vv);
      ovv[j] = f2bs(vv);
    }
    *reinterpret_cast<short8*>(&xw[px0][n0 * 64 + c00]) = ovv;
  }
  int it1 = t + 512;
  int qi1 = it1 >> 3, c01 = (it1 & 7) * 8;
  int px1 = qi1 / 5, n1 = 4 + (qi1 - px1 * 5);
  int q1 = px1 * 9 + n1;
  float4v g1 = *reinterpret_cast<const float4v*>(gw[q1]);
  int bL1 = ga[q1][0] + c01, bR1 = ga[q1][1] + c01;
  short8 A01 = *reinterpret_cast<const short8*>(xpb + bL1);
  short8 A11 = *reinterpret_cast<const short8*>(xpb + bL1 + 64);
  short8 A21 = *reinterpret_cast<const short8*>(xpb + bR1);
  short8 A31 = *reinterpret_cast<const short8*>(xpb + bR1 + 64);

  // GEMM ks 4..5
  #pragma unroll
  for (int ks = 4; ks < 6; ++ks) {
    short8 a = *reinterpret_cast<const short8*>(wtw + ks * 32 + quad * 8);
    short8 bfr = *reinterpret_cast<const short8*>(&xw[xrow][ks * 32 + quad * 8]);
    acc = __builtin_amdgcn_mfma_f32_16x16x32_bf16(a, bfr, acc, 0, 0, 0);
  }

  // convert + store rep1; prefetch rep2 (tasks t+1024; valid t<256)
  {
    short8 ovv;
    #pragma unroll
    for (int j = 0; j < 8; ++j) {
      float vv = g1.x * s2f(A01[j]);
      vv = fmaf(g1.y, s2f(A11[j]), vv);
      vv = fmaf(g1.z, s2f(A21[j]), vv);
      vv = fmaf(g1.w, s2f(A31[j]), vv);
      ovv[j] = f2bs(vv);
    }
    *reinterpret_cast<short8*>(&xw[px1][n1 * 64 + c01]) = ovv;
  }
  bool ok2 = (t < 256);
  int it2 = t + 1024;
  int qi2 = it2 >> 3, c02 = (it2 & 7) * 8;
  int px2 = qi2 / 5, n2 = 4 + (qi2 - px2 * 5);
  int q2 = px2 * 9 + n2;
  float4v g2 = {0.f,0.f,0.f,0.f};
  short8 A02, A12, A22, A32;
  if (ok2) {
    g2 = *reinterpret_cast<const float4v*>(gw[q2]);
    int bL2 = ga[q2][0] + c02, bR2 = ga[q2][1] + c02;
    A02 = *reinterpret_cast<const short8*>(xpb + bL2);
    A12 = *reinterpret_cast<const short8*>(xpb + bL2 + 64);
    A22 = *reinterpret_cast<const short8*>(xpb + bR2);
    A32 = *reinterpret_cast<const short8*>(xpb + bR2 + 64);
  }

  // GEMM ks 6..7
  #pragma unroll
  for (int ks = 6; ks < 8; ++ks) {
    short8 a = *reinterpret_cast<const short8*>(wtw + ks * 32 + quad * 8);
    short8 bfr = *reinterpret_cast<const short8*>(&xw[xrow][ks * 32 + quad * 8]);
    acc = __builtin_amdgcn_mfma_f32_16x16x32_bf16(a, bfr, acc, 0, 0, 0);
  }

  // convert + store rep2
  if (ok2) {
    short8 ovv;
    #pragma unroll
    for (int j = 0; j < 8; ++j) {
      float vv = g2.x * s2f(A02[j]);
      vv = fmaf(g2.y, s2f(A12[j]), vv);
      vv = fmaf(g2.z, s2f(A22[j]), vv);
      vv = fmaf(g2.w, s2f(A32[j]), vv);
      ovv[j] = f2bs(vv);
    }
    *reinterpret_cast<short8*>(&xw[px2][n2 * 64 + c02]) = ovv;
  }
  __syncthreads();

  // ---- phase 5b: GEMM ks 8..17 (taps 4-8) + out write ----
  #pragma unroll
  for (int ks = 8; ks < 18; ++ks) {
    short8 a = *reinterpret_cast<const short8*>(wtw + ks * 32 + quad * 8);
    short8 bfr = *reinterpret_cast<const short8*>(&xw[xrow][ks * 32 + quad * 8]);
    acc = __builtin_amdgcn_mfma_f32_16x16x32_bf16(a, bfr, acc, 0, 0, 0);
  }
  #pragma unroll
  for (int r = 0; r < 4; ++r) {
    int co = ct*16 + quad * 4 + r;
    out_x[((b * Cc + co) * Hh + h) * Wd + w0 + pg5*16 + mrow] = acc[r];
  }
}

// ---------------------------------------------------------------------------
// Fallback (R9-verified scalar pipeline; zero ws)
// ---------------------------------------------------------------------------
__global__ void f_convAB(const float* __restrict__ x, const float* __restrict__ po,
                         const float* __restrict__ wA, const float* __restrict__ bA,
                         const float* __restrict__ wB, const float* __restrict__ bB,
                         float* __restrict__ u_scr, float* __restrict__ ro_scr) {
  int idx = blockIdx.x * 256 + threadIdx.x;
  if (idx >= Bn * MHc * HW) return;
  int w = idx & 127, h = (idx >> 7) & 127, oc = (idx >> 14) % MHc, b = idx / (MHc*HW);
  float accA = bA[oc], accB = bB[oc];
  const float* xb = x + b*Cc*HW; const float* pb = po + b*MHc*HW;
  for (int ic = 0; ic < Cc + MHc; ++ic) {
    const float* src = (ic < Cc) ? (xb + ic*HW) : (pb + (ic-Cc)*HW);
    const float* wa = wA + (oc*(Cc+MHc)+ic)*9; const float* wb = wB + (oc*(Cc+MHc)+ic)*9;
    for (int kh = 0; kh < 3; ++kh) { int hh = h+kh-1; if ((unsigned)hh >= Hh) continue;
      for (int kw = 0; kw < 3; ++kw) { int ww = w+kw-1; if ((unsigned)ww >= Wd) continue;
        float v = src[hh*Wd+ww]; accA += v*wa[kh*3+kw]; accB += v*wb[kh*3+kw]; } }
  }
  u_scr[idx] = sigm(accA); ro_scr[idx] = sigm(accB) * pb[oc*HW + h*Wd + w];
}
__global__ void f_convC(const float* __restrict__ x, const float* __restrict__ po,
                        const float* __restrict__ mean, const float* __restrict__ wC,
                        const float* __restrict__ bC, const float* __restrict__ u_scr,
                        const float* __restrict__ ro_scr, float* __restrict__ out_off,
                        float* __restrict__ out_mean) {
  int idx = blockIdx.x * 256 + threadIdx.x;
  if (idx >= Bn * MHc * HW) return;
  int w = idx & 127, h = (idx >> 7) & 127, oc = (idx >> 14) % MHc, b = idx / (MHc*HW);
  float acc = bC[oc];
  const float* xb = x + b*Cc*HW; const float* rb = ro_scr + b*MHc*HW;
  for (int ic = 0; ic < Cc + MHc; ++ic) {
    const float* src = (ic < Cc) ? (xb + ic*HW) : (rb + (ic-Cc)*HW);
    const float* wv = wC + (oc*(Cc+MHc)+ic)*9;
    for (int kh = 0; kh < 3; ++kh) { int hh = h+kh-1; if ((unsigned)hh >= Hh) continue;
      for (int kw = 0; kw < 3; ++kw) { int ww = w+kw-1; if ((unsigned)ww >= Wd) continue;
        acc += src[hh*Wd+ww]*wv[kh*3+kw]; } }
  }
  float cand = tanhf(acc); float u = u_scr[idx]; float p = po[idx];
  float mn = 0.5f*(mean[idx]+p);
  out_off[idx] = p*(1.f-u)+cand*u+mn; out_mean[idx] = mn;
}
__global__ __launch_bounds__(256)
void f_warp(const float* __restrict__ x, const float* __restrict__ off_f,
            const float* __restrict__ wg, const float* __restrict__ bg,
            const float* __restrict__ wc, float* __restrict__ out) {
  __shared__ float mred[4][Np][64]; __shared__ float mval[4][Np];
  __shared__ float xwv[4][Np][64];
  int lane = threadIdx.x & 63, wave = threadIdx.x >> 6;
  int p = blockIdx.x * 4 + wave;
  int b = p >> 14, rem = p & 16383, h = rem >> 7, w = rem & 127;
  const float* xc = x + (b*Cc + lane)*HW;
  float part[Np];
  for (int n = 0; n < Np; ++n) part[n] = 0.f;
  for (int kh = 0; kh < 3; ++kh) { int hh = h+kh-1; if ((unsigned)hh >= Hh) continue;
    for (int kw = 0; kw < 3; ++kw) { int ww = w+kw-1; if ((unsigned)ww >= Wd) continue;
      float v = xc[hh*Wd+ww];
      for (int n = 0; n < Np; ++n) part[n] += v*wg[(n*Cc+lane)*9+kh*3+kw]; } }
  for (int n = 0; n < Np; ++n) mred[wave][n][lane] = part[n];
  __syncthreads();
  if (lane < Np) { float s = bg[lane];
    for (int c = 0; c < Cc; ++c) s += mred[wave][lane][c];
    mval[wave][lane] = sigm(s); }
  __syncthreads();
  const float* offb = off_f + b*MHc*HW; int sp = h*Wd + w;
  for (int n = 0; n < Np; ++n) {
    float px = (float)(h+1) + (float)(n/3-1) + offb[n*HW+sp];
    float py = (float)(w+1) + (float)(n%3-1) + offb[(9+n)*HW+sp];
    float fxq = floorf(px), fyq = floorf(py);
    float xlt = fminf(fmaxf(fxq,0.f),129.f), ylt = fminf(fmaxf(fyq,0.f),129.f);
    float xrb = fminf(fmaxf(fxq+1.f,0.f),129.f), yrb = fminf(fmaxf(fyq+1.f,0.f),129.f);
    float pxc = fminf(fmaxf(px,0.f),129.f), pyc = fminf(fmaxf(py,0.f),129.f);
    float glt = (1.f+xlt-pxc)*(1.f+ylt-pyc), grb = (1.f-xrb+pxc)*(1.f-yrb+pyc);
    float glb = (1.f+xlt-pxc)*(1.f-yrb+pyc), grt = (1.f-xrb+pxc)*(1.f+ylt-pyc);
    int ixl=(int)xlt, iyl=(int)ylt, ixr=(int)xrb, iyr=(int)yrb;
    float vlt=0.f,vrb=0.f,vlb=0.f,vrt=0.f;
    if (ixl>=1&&ixl<=Hh&&iyl>=1&&iyl<=Wd) vlt = xc[(ixl-1)*Wd+(iyl-1)];
    if (ixr>=1&&ixr<=Hh&&iyr>=1&&iyr<=Wd) vrb = xc[(ixr-1)*Wd+(iyr-1)];
    if (ixl>=1&&ixl<=Hh&&iyr>=1&&iyr<=Wd) vlb = xc[(ixl-1)*Wd+(iyr-1)];
    if (ixr>=1&&ixr<=Hh&&iyl>=1&&iyl<=Wd) vrt = xc[(ixr-1)*Wd+(iyl-1)];
    xwv[wave][n][lane] = (glt*vlt+grb*vrb+glb*vlb+grt*vrt)*mval[wave][n];
  }
  __syncthreads();
  float acc = 0.f;
  for (int c = 0; c < Cc; ++c)
    for (int n = 0; n < Np; ++n)
      acc += xwv[wave][n][c]*wc[(lane*Cc+c)*9+n];
  out[(b*Cc+lane)*HW + h*Wd + w] = acc;
}

// ---------------------------------------------------------------------------
extern "C" void kernel_launch(void* const* d_in, const int* in_sizes, int n_in,
                              void* d_out, int out_size, void* d_ws, size_t ws_size,
                              hipStream_t stream) {
  (void)in_sizes; (void)n_in; (void)out_size;
  const float* x_t   = (const float*)d_in[0];
  const float* po    = (const float*)d_in[1];
  const float* mean  = (const float*)d_in[2];
  const float* upd_w = (const float*)d_in[3];
  const float* upd_b = (const float*)d_in[4];
  const float* rst_w = (const float*)d_in[5];
  const float* rst_b = (const float*)d_in[6];
  const float* out_w = (const float*)d_in[7];
  const float* out_b = (const float*)d_in[8];
  const float* wg_w  = (const float*)d_in[9];
  const float* wg_b  = (const float*)d_in[10];
  const float* wcw   = (const float*)d_in[11];

  float* out_x   = (float*)d_out;            // [4,64,128,128]
  float* out_off = out_x + 4194304;          // [4,18,128,128]
  float* out_mn  = out_off + 1179648;        // [4,18,128,128]

  char* ws = (char*)d_ws;
  __hip_bfloat16* xpad  = (__hip_bfloat16*)(ws + 0);          //  8,652,800
  __hip_bfloat16* popad = (__hip_bfloat16*)(ws + 8652800);    //  4,326,400
  __hip_bfloat16* ropad = (__hip_bfloat16*)(ws + 12979200);   //  4,326,400
  __hip_bfloat16* wall  = (__hip_bfloat16*)(ws + 17305600);   //    110,592
  __hip_bfloat16* w2    = (__hip_bfloat16*)(ws + 17416192);   //     18,432
  __hip_bfloat16* wt_bf = (__hip_bfloat16*)(ws + 17434624);   //     73,728
  __hip_bfloat16* m_t   = (__hip_bfloat16*)(ws + 17508352);   //  1,179,648
  const size_t WS_NEED = 18688000;

  if (ws_size >= WS_NEED) {
    // no memset: pad borders zeroed by k_prep's border blocks; popad interior
    // ch 18..31 zeroed in the po-part; all other ws regions fully written.
    hipLaunchKernelGGL(k_prep,  dim3(1432), dim3(256), 0, stream,
                       x_t, po, upd_w, rst_w, out_w, wg_w, wcw,
                       xpad, popad, ropad, wall, w2, wt_bf);
    // u -> out_mn region, cx -> out_off region (exact [B,18,HW] aliases;
    // k_fuse reads each address before overwriting it)
    hipLaunchKernelGGL(k_gates, dim3(2048), dim3(256), 0, stream,
                       xpad, popad, wall, po, upd_b, rst_b, out_b, wg_b,
                       out_mn, out_off, ropad, m_t);
    hipLaunchKernelGGL(k_fuse,  dim3(2048), dim3(512), 0, stream,
                       xpad, ropad, w2, wt_bf, m_t, po, mean,
                       out_off, out_mn, out_x);
  } else {
    float* u_scr  = out_x;
    float* cx_scr = out_x + 1179648;
    hipLaunchKernelGGL(f_convAB, dim3(4608), dim3(256), 0, stream,
                       x_t, po, upd_w, upd_b, rst_w, rst_b, u_scr, cx_scr);
    hipLaunchKernelGGL(f_convC,  dim3(4608), dim3(256), 0, stream,
                       x_t, po, mean, out_w, out_b, u_scr, cx_scr,
                       out_off, out_mn);
    hipLaunchKernelGGL(f_warp,   dim3(16384), dim3(256), 0, stream,
                       x_t, out_off, wg_w, wg_b, wcw, out_x);
  }
}